// Round 15
// baseline (501.222 us; speedup 1.0000x reference)
//
#include <hip/hip_runtime.h>
#include <hip/hip_bf16.h>

using short8  = __attribute__((ext_vector_type(8))) short;
using ushort8 = __attribute__((ext_vector_type(8))) unsigned short;
using f32x4   = __attribute__((ext_vector_type(4))) float;
using fvec4   = __attribute__((ext_vector_type(4))) float;

#define CH 8192   // edges per hist/scatter block

__device__ inline unsigned short f2bf(float x) {
  union { __hip_bfloat16 b; unsigned short u; } c;
  c.b = __float2bfloat16(x);
  return c.u;
}
__device__ inline float bf2f(unsigned short s) {
  return __uint_as_float(((unsigned int)s) << 16);
}
__device__ inline unsigned int pk2(float lo, float hi) {
  union { __hip_bfloat162 b; unsigned int u; } c;
  c.b = __float22bfloat162_rn(make_float2(lo, hi));
  return c.u;
}
// 8 f32 -> short8 of bf16 via v_cvt_pk_bf16_f32
__device__ inline short8 cvt8(fvec4 a, fvec4 b) {
  union { short8 s; unsigned int u[4]; } r;
  r.u[0] = pk2(a[0], a[1]);
  r.u[1] = pk2(a[2], a[3]);
  r.u[2] = pk2(b[0], b[1]);
  r.u[3] = pk2(b[2], b[3]);
  return r.s;
}

// async 16B global->LDS copy (per-lane global src, wave-uniform LDS base + lane*16)
__device__ inline void gload_lds16(const void* g, void* l) {
  __builtin_amdgcn_global_load_lds(
      (const __attribute__((address_space(1))) void*)g,
      (__attribute__((address_space(3))) void*)l, 16, 0, 0);
}

// B fragments for [64x64] W (row-major f32): lane holds B[k=ks*32+lh*8+i][col=ct*16+l15]
__device__ inline void load_bfrags_f32(const float* __restrict__ W, short8 bfr[2][4], int lane) {
  int l15 = lane & 15, lh = lane >> 4;
#pragma unroll
  for (int ks = 0; ks < 2; ++ks)
#pragma unroll
    for (int ct = 0; ct < 4; ++ct) {
      short8 v;
#pragma unroll
      for (int i = 0; i < 8; ++i)
        v[i] = (short)f2bf(W[(ks * 32 + lh * 8 + i) * 64 + ct * 16 + l15]);
      bfr[ks][ct] = v;
    }
}

// pre-fragmented bf16 W: frag (ks,ct) for lane at Wf[((ks*4+ct)<<9) + (lane<<3)]
__device__ inline void load_bfrags(const unsigned short* __restrict__ Wf, short8 bfr[2][4], int lane) {
#pragma unroll
  for (int ks = 0; ks < 2; ++ks)
#pragma unroll
    for (int ct = 0; ct < 4; ++ct) {
      union { ushort8 u; short8 s; } c;
      c.u = *reinterpret_cast<const ushort8*>(Wf + (((ks * 4 + ct) << 9) + (lane << 3)));
      bfr[ks][ct] = c.s;
    }
}

struct PrepArgs {
  const float* W[10];
};

// one-time: convert 10 [64x64] f32 W matrices into MFMA fragment-layout bf16
__global__ __launch_bounds__(64) void prep_w_kernel(PrepArgs pw, unsigned short* __restrict__ Wf) {
  int z = blockIdx.x;
  int lane = threadIdx.x & 63;
  short8 bfr[2][4];
  load_bfrags_f32(pw.W[z], bfr, lane);
  unsigned short* dst = Wf + (size_t)z * 4096;
#pragma unroll
  for (int ks = 0; ks < 2; ++ks)
#pragma unroll
    for (int ct = 0; ct < 4; ++ct) {
      union { short8 s; ushort8 u; } c;
      c.s = bfr[ks][ct];
      *reinterpret_cast<ushort8*>(dst + (((ks * 4 + ct) << 9) + (lane << 3))) = c.u;
    }
}

struct ProjArgs {
  unsigned short* out[6];
};

// two projections per block (z = 2*blockIdx.y + {0,1}); h fragments loaded ONCE
__global__ __launch_bounds__(256) void proj_all_kernel(const float* __restrict__ h,
                                                       const unsigned short* __restrict__ Wf,
                                                       ProjArgs pa, int N) {
  int zb = blockIdx.y * 2;
  int lane = threadIdx.x & 63;
  int wv = threadIdx.x >> 6;
  int rowbase = blockIdx.x * 256 + wv * 64;
  int l15 = lane & 15, lh = lane >> 4;

  short8 afr[4][2];
#pragma unroll
  for (int rt = 0; rt < 4; ++rt) {
    int row = rowbase + rt * 16 + l15;
    int rc = row < N ? row : 0;
    const fvec4* p = reinterpret_cast<const fvec4*>(h + (size_t)rc * 64);
#pragma unroll
    for (int ks = 0; ks < 2; ++ks)
      afr[rt][ks] = cvt8(p[ks * 8 + lh * 2], p[ks * 8 + lh * 2 + 1]);
  }

  for (int zi = 0; zi < 2; ++zi) {
    int z = zb + zi;
    short8 bfr[2][4];
    load_bfrags(Wf + (size_t)z * 4096, bfr, lane);
    unsigned short* __restrict__ out = pa.out[z];

    f32x4 acc[4][4];
#pragma unroll
    for (int rt = 0; rt < 4; ++rt)
#pragma unroll
      for (int ct = 0; ct < 4; ++ct) acc[rt][ct] = (f32x4){0.f, 0.f, 0.f, 0.f};

#pragma unroll
    for (int rt = 0; rt < 4; ++rt)
#pragma unroll
      for (int ks = 0; ks < 2; ++ks)
#pragma unroll
        for (int ct = 0; ct < 4; ++ct)
          acc[rt][ct] = __builtin_amdgcn_mfma_f32_16x16x32_bf16(afr[rt][ks], bfr[ks][ct], acc[rt][ct], 0, 0, 0);

#pragma unroll
    for (int rt = 0; rt < 4; ++rt)
#pragma unroll
      for (int rg = 0; rg < 4; ++rg) {
        int row = rowbase + rt * 16 + lh * 4 + rg;
        if (row < N) {
#pragma unroll
          for (int ct = 0; ct < 4; ++ct)
            out[(size_t)row * 64 + ct * 16 + l15] = f2bf(acc[rt][ct][rg]);
        }
      }
  }
}

// ---- bucket histogram (bin = dst>>6), LDS-aggregated ----
__global__ __launch_bounds__(256) void hist_kernel(const int* __restrict__ dst0, const int* __restrict__ dst1,
                                                   int* __restrict__ counts, int E, int NBK) {
  __shared__ int hcnt[2048];
  int z = blockIdx.y;
  const int* __restrict__ dst = z ? dst1 : dst0;
  int t = threadIdx.x;
  for (int i = t; i < NBK; i += 256) hcnt[i] = 0;
  __syncthreads();
  int base = blockIdx.x * CH;
#pragma unroll 4
  for (int k = 0; k < CH / 256; ++k) {
    int i = base + k * 256 + t;
    if (i < E) atomicAdd(&hcnt[dst[i] >> 6], 1);
  }
  __syncthreads();
  for (int i = t; i < NBK; i += 256) {
    int c = hcnt[i];
    if (c) atomicAdd(&counts[(size_t)z * NBK + i], c);
  }
}

// exclusive scan of bucket counts -> cursor (preserved) and gcur (working copy)
__global__ __launch_bounds__(1024) void scan_kernel(const int* __restrict__ counts, int* __restrict__ cursor,
                                                    int* __restrict__ gcur, int NBK) {
  int z = blockIdx.x;
  const int* c = counts + (size_t)z * NBK;
  __shared__ int lds[1024];
  int t = threadIdx.x;
  int carry = 0;
  for (int base = 0; base < NBK; base += 1024) {
    int i = base + t;
    int v = (i < NBK) ? c[i] : 0;
    lds[t] = v;
    __syncthreads();
    for (int off = 1; off < 1024; off <<= 1) {
      int x = (t >= off) ? lds[t - off] : 0;
      __syncthreads();
      lds[t] += x;
      __syncthreads();
    }
    if (i < NBK) {
      int excl = carry + lds[t] - v;
      cursor[(size_t)z * NBK + i] = excl;
      gcur[(size_t)z * NBK + i] = excl;
    }
    carry += lds[1023];
    __syncthreads();
  }
}

// ---- phase A: bucket scatter with per-block rank aggregation ----
// packed record: x = el | (bin<<21)   (el<2^21, bin<2^11)
//                y = src | (dl<<26)   (src<2^26, dl<64)
__global__ __launch_bounds__(256) void scatterA_kernel(
    const int* __restrict__ src0, const int* __restrict__ dst0,
    const int* __restrict__ src1, const int* __restrict__ dst1,
    int* __restrict__ gcur, int2* __restrict__ recs0, int2* __restrict__ recs1,
    int E, int NBK) {
  __shared__ int lcnt[2048];
  int z = blockIdx.y;
  const int* __restrict__ src = z ? src1 : src0;
  const int* __restrict__ dst = z ? dst1 : dst0;
  int2* __restrict__ recs = z ? recs1 : recs0;
  int t = threadIdx.x;
  for (int i = t; i < NBK; i += 256) lcnt[i] = 0;
  __syncthreads();
  int base = blockIdx.x * CH;
#pragma unroll 4
  for (int k = 0; k < CH / 256; ++k) {
    int i = base + k * 256 + t;
    if (i < E) atomicAdd(&lcnt[dst[i] >> 6], 1);
  }
  __syncthreads();
  for (int i = t; i < NBK; i += 256) {
    int c = lcnt[i];
    lcnt[i] = c ? atomicAdd(&gcur[(size_t)z * NBK + i], c) : 0;
  }
  __syncthreads();
#pragma unroll 4
  for (int k = 0; k < CH / 256; ++k) {
    int i = base + k * 256 + t;
    if (i < E) {
      int d = dst[i], s = src[i];
      int bin = d >> 6, dl = d & 63;
      int pos = atomicAdd(&lcnt[bin], 1);
      recs[pos] = make_int2(i | (bin << 21), s | (dl << 26));
    }
  }
}

// ---- phase B: in-bucket counting sort by dl, IN PLACE (bucket region is block-exclusive) ----
__global__ __launch_bounds__(256) void sortB_kernel(int2* __restrict__ recs0, int2* __restrict__ recs1,
                                                    const int* __restrict__ cursor,
                                                    const int* __restrict__ counts, int NBK) {
  __shared__ int cnt_lds[64];
  __shared__ int cur_lds[64];
  int z = blockIdx.y;
  int b = blockIdx.x;
  int2* __restrict__ recs = z ? recs1 : recs0;
  int start = cursor[(size_t)z * NBK + b];
  int cnt = counts[(size_t)z * NBK + b];
  int t = threadIdx.x;

  for (int cbase = 0; cbase < cnt; cbase += 2048) {
    int ccnt = min(2048, cnt - cbase);
    int2 r[8];
    int dl[8];
    if (t < 64) cnt_lds[t] = 0;
    __syncthreads();
#pragma unroll
    for (int k = 0; k < 8; ++k) {
      int idx = k * 256 + t;
      if (idx < ccnt) {
        r[k] = recs[start + cbase + idx];
        dl[k] = ((unsigned)r[k].y) >> 26;
        atomicAdd(&cnt_lds[dl[k]], 1);
      }
    }
    __syncthreads();
    if (t < 64) {  // wave 0: exclusive prefix over 64 bins
      int c = cnt_lds[t];
      int x = c;
#pragma unroll
      for (int off = 1; off < 64; off <<= 1) {
        int y = __shfl_up(x, off);
        if (t >= off) x += y;
      }
      cur_lds[t] = x - c;
    }
    __syncthreads();
#pragma unroll
    for (int k = 0; k < 8; ++k) {
      int idx = k * 256 + t;
      if (idx < ccnt) {
        int pos = atomicAdd(&cur_lds[dl[k]], 1);
        recs[start + cbase + pos] = r[k];
      }
    }
    __syncthreads();
  }
}

struct EdgeArgs {
  const float* e[2];
  const int2* recs[2];
  const unsigned short* We[2];
  const float* bmsg[2];
  const unsigned short* Ps[2];
  const unsigned short* Pd[2];
  float* agg[2];
};

// ---- edge GEMM over dst-sorted 16-edge tiles; ALL gathers async into LDS ----
// 8KB LDS/wave (e 4KB + Ps 2KB + Pd 2KB), ~85 regs -> 5 blocks/CU x 4 waves = 62% cap.
// One async batch (8 gloads), one vmcnt(0), Ps/Pd read as bf16 A-frags from LDS.
__global__ __launch_bounds__(256) void edge_sorted_kernel(EdgeArgs ea, int E) {
  __shared__ char lds_all[4][8192];  // per wave: e @0 (4KB), Ps @4096 (2KB), Pd @6144 (2KB)

  int z = blockIdx.y;
  const float* __restrict__ e = ea.e[z];
  const int2* __restrict__ recs = ea.recs[z];
  const unsigned short* __restrict__ Psrc = ea.Ps[z];
  const unsigned short* __restrict__ Pdst = ea.Pd[z];
  float* __restrict__ agg = ea.agg[z];

  int lane = threadIdx.x & 63;
  int wv = threadIdx.x >> 6;
  int base = (blockIdx.x * 4 + wv) * 16;
  if (base >= E) return;  // no barriers; LDS wave-private -> safe
  int l15 = lane & 15, lh = lane >> 4;
  char* lb = &lds_all[wv][0];

  // this wave's 16 sorted slots (all quarters replicate; 8B coalesced)
  int slot = base + l15;
  int el = 0, sl = 0, dl = 0;
  if (slot < E) {
    int2 rc = recs[slot];
    el = rc.x & 0x1FFFFF;
    sl = rc.y & 0x3FFFFFF;
    dl = (((rc.x >> 21) & 0x7FF) << 6) | (int)(((unsigned)rc.y) >> 26);
  }

  // ---- async staging batch: e (4x), Ps (2x), Pd (2x), all swizzled via source perm ----
  // e rows 256B: instr i covers rows r=i*4+(lane>>4); chunk slot s=lane&15; src chunk c=s^(r&7).
#pragma unroll
  for (int i = 0; i < 4; ++i) {
    int r = i * 4 + (lane >> 4);
    int er = __shfl(el, r);
    int c = (lane & 15) ^ (r & 7);
    gload_lds16(e + ((size_t)er << 6) + c * 4, lb + i * 1024);
  }
  // Ps rows 128B: instr i covers rows r=i*8+(lane>>3); slot s=lane&7; src chunk c=s^(r&7).
#pragma unroll
  for (int i = 0; i < 2; ++i) {
    int r = i * 8 + (lane >> 3);
    int hr = __shfl(sl, r);
    int c = (lane & 7) ^ (r & 7);
    gload_lds16(Psrc + ((size_t)hr << 6) + c * 8, lb + 4096 + i * 1024);
  }
#pragma unroll
  for (int i = 0; i < 2; ++i) {
    int r = i * 8 + (lane >> 3);
    int dr = __shfl(dl, r);
    int c = (lane & 7) ^ (r & 7);
    gload_lds16(Pdst + ((size_t)dr << 6) + c * 8, lb + 6144 + i * 1024);
  }
  __builtin_amdgcn_sched_barrier(0);

  // uniform data while gathers fly
  const float* bmsg = ea.bmsg[z];
  float bv[4];
#pragma unroll
  for (int ct = 0; ct < 4; ++ct) bv[ct] = bmsg[ct * 16 + l15];

  short8 bfr[2][4];
  load_bfrags(ea.We[z], bfr, lane);

  short8 idf[2];
#pragma unroll
  for (int half = 0; half < 2; ++half) {
    short8 v;
#pragma unroll
    for (int i = 0; i < 8; ++i)
      v[i] = (short)((lh * 8 + i == half * 16 + l15) ? 0x3F80 : 0);
    idf[half] = v;
  }

  f32x4 acc[4];
#pragma unroll
  for (int ct = 0; ct < 4; ++ct)
    acc[ct] = (f32x4){bv[ct], bv[ct], bv[ct], bv[ct]};

  // ---- single drain, then all MFMAs from LDS ----
  asm volatile("s_waitcnt vmcnt(0)" ::: "memory");
  __builtin_amdgcn_sched_barrier(0);

  int r = l15;
  int xs = r & 7;

  // Ps/Pd A-frags (bf16 in LDS, no conversion)
  union { ushort8 u; short8 s; } aP0, aP1, aD0, aD1;
  aP0.u = *reinterpret_cast<ushort8*>(lb + 4096 + (r << 7) + (((lh) ^ xs) << 4));
  aP1.u = *reinterpret_cast<ushort8*>(lb + 4096 + (r << 7) + (((4 + lh) ^ xs) << 4));
  aD0.u = *reinterpret_cast<ushort8*>(lb + 6144 + (r << 7) + (((lh) ^ xs) << 4));
  aD1.u = *reinterpret_cast<ushort8*>(lb + 6144 + (r << 7) + (((4 + lh) ^ xs) << 4));
  acc[0] = __builtin_amdgcn_mfma_f32_16x16x32_bf16(aP0.s, idf[0], acc[0], 0, 0, 0);
  acc[1] = __builtin_amdgcn_mfma_f32_16x16x32_bf16(aP0.s, idf[1], acc[1], 0, 0, 0);
  acc[2] = __builtin_amdgcn_mfma_f32_16x16x32_bf16(aP1.s, idf[0], acc[2], 0, 0, 0);
  acc[3] = __builtin_amdgcn_mfma_f32_16x16x32_bf16(aP1.s, idf[1], acc[3], 0, 0, 0);
  acc[0] = __builtin_amdgcn_mfma_f32_16x16x32_bf16(aD0.s, idf[0], acc[0], 0, 0, 0);
  acc[1] = __builtin_amdgcn_mfma_f32_16x16x32_bf16(aD0.s, idf[1], acc[1], 0, 0, 0);
  acc[2] = __builtin_amdgcn_mfma_f32_16x16x32_bf16(aD1.s, idf[0], acc[2], 0, 0, 0);
  acc[3] = __builtin_amdgcn_mfma_f32_16x16x32_bf16(aD1.s, idf[1], acc[3], 0, 0, 0);

  // e A-frags (f32 in LDS -> cvt)
  {
    int rb = r << 8;
    fvec4 p0 = *reinterpret_cast<const fvec4*>(lb + rb + (((lh * 2) ^ xs) << 4));
    fvec4 p1 = *reinterpret_cast<const fvec4*>(lb + rb + (((lh * 2 + 1) ^ xs) << 4));
    fvec4 p2 = *reinterpret_cast<const fvec4*>(lb + rb + (((8 + lh * 2) ^ xs) << 4));
    fvec4 p3 = *reinterpret_cast<const fvec4*>(lb + rb + (((9 + lh * 2) ^ xs) << 4));
    short8 aE0 = cvt8(p0, p1);
    short8 aE1 = cvt8(p2, p3);
#pragma unroll
    for (int ct = 0; ct < 4; ++ct) {
      acc[ct] = __builtin_amdgcn_mfma_f32_16x16x32_bf16(aE0, bfr[0][ct], acc[ct], 0, 0, 0);
      acc[ct] = __builtin_amdgcn_mfma_f32_16x16x32_bf16(aE1, bfr[1][ct], acc[ct], 0, 0, 0);
    }
  }

  // relu in place
#pragma unroll
  for (int ct = 0; ct < 4; ++ct)
#pragma unroll
    for (int rg = 0; rg < 4; ++rg)
      acc[ct][rg] = fmaxf(acc[ct][rg], 0.f);

  // ---- segmented flush (16 rows), all in registers ----
  int dprev = __shfl_up(dl, 1);
  unsigned long long bnd = __ballot(lane > 0 && dl != dprev) & 0xFFFFull;
  int vrows = min(16, E - base);  // wave-uniform

  int r0 = 0;
  while (r0 < vrows) {
    unsigned long long rest = bnd >> (r0 + 1);
    int r1 = rest ? (r0 + 1 + __builtin_ctzll(rest)) : 16;
    if (r1 > vrows) r1 = vrows;
    int dcur = __shfl(dl, r0);

    float s0 = 0.f, s1 = 0.f, s2 = 0.f, s3 = 0.f;
    if (r0 == 0 && r1 == 16) {  // whole tile (common case)
#pragma unroll
      for (int rg = 0; rg < 4; ++rg) {
        s0 += acc[0][rg];
        s1 += acc[1][rg];
        s2 += acc[2][rg];
        s3 += acc[3][rg];
      }
    } else {
#pragma unroll
      for (int rg = 0; rg < 4; ++rg) {
        int row = lh * 4 + rg;
        bool in = (row >= r0) && (row < r1);
        s0 += in ? acc[0][rg] : 0.f;
        s1 += in ? acc[1][rg] : 0.f;
        s2 += in ? acc[2][rg] : 0.f;
        s3 += in ? acc[3][rg] : 0.f;
      }
    }
    // reduce across the 4 lh-lanes of each column group
    s0 += __shfl_xor(s0, 16); s0 += __shfl_xor(s0, 32);
    s1 += __shfl_xor(s1, 16); s1 += __shfl_xor(s1, 32);
    s2 += __shfl_xor(s2, 16); s2 += __shfl_xor(s2, 32);
    s3 += __shfl_xor(s3, 16); s3 += __shfl_xor(s3, 32);
    // lane (lh,l15) owns column lh*16+l15 == lane
    float mine = (lh == 0) ? s0 : (lh == 1) ? s1 : (lh == 2) ? s2 : s3;
    atomicAdd(&agg[(size_t)dcur * 64 + lane], mine);
    r0 = r1;
  }
}

struct NodeArgs {
  const float* agg[2];
  const unsigned short* T[2];
  const float* bn[2];
  unsigned short* U[2];
};

// U = bf16(relu(T + agg@Wagg + b_node)); agg split hi+lo bf16 for accuracy
__global__ __launch_bounds__(256) void node_kernel(const unsigned short* __restrict__ Wf,
                                                   NodeArgs na, int N) {
  int z = blockIdx.y;
  const float* __restrict__ agg = na.agg[z];
  const unsigned short* __restrict__ T = na.T[z];
  const float* __restrict__ bn = na.bn[z];
  unsigned short* __restrict__ U = na.U[z];
  int lane = threadIdx.x & 63;
  int wv = threadIdx.x >> 6;
  int rowbase = blockIdx.x * 256 + wv * 64;
  int l15 = lane & 15, lh = lane >> 4;

  short8 bfr[2][4];
  load_bfrags(Wf + (size_t)(8 + z) * 4096, bfr, lane);

  f32x4 acc[4][4];
#pragma unroll
  for (int rt = 0; rt < 4; ++rt)
#pragma unroll
    for (int ct = 0; ct < 4; ++ct) acc[rt][ct] = (f32x4){0.f, 0.f, 0.f, 0.f};

#pragma unroll
  for (int rt = 0; rt < 4; ++rt) {
    int row = rowbase + rt * 16 + l15;
    int rc = row < N ? row : 0;
    const fvec4* p = reinterpret_cast<const fvec4*>(agg + (size_t)rc * 64);
#pragma unroll
    for (int ks = 0; ks < 2; ++ks) {
      fvec4 p0 = p[ks * 8 + lh * 2], p1 = p[ks * 8 + lh * 2 + 1];
      short8 ahi = cvt8(p0, p1);
      fvec4 q0, q1;
#pragma unroll
      for (int i = 0; i < 4; ++i) {
        q0[i] = p0[i] - bf2f((unsigned short)ahi[i]);
        q1[i] = p1[i] - bf2f((unsigned short)ahi[i + 4]);
      }
      short8 alo = cvt8(q0, q1);
#pragma unroll
      for (int ct = 0; ct < 4; ++ct) {
        acc[rt][ct] = __builtin_amdgcn_mfma_f32_16x16x32_bf16(ahi, bfr[ks][ct], acc[rt][ct], 0, 0, 0);
        acc[rt][ct] = __builtin_amdgcn_mfma_f32_16x16x32_bf16(alo, bfr[ks][ct], acc[rt][ct], 0, 0, 0);
      }
    }
  }

  float bv[4];
#pragma unroll
  for (int ct = 0; ct < 4; ++ct) bv[ct] = bn[ct * 16 + l15];

#pragma unroll
  for (int rt = 0; rt < 4; ++rt)
#pragma unroll
    for (int rg = 0; rg < 4; ++rg) {
      int row = rowbase + rt * 16 + lh * 4 + rg;
      if (row < N) {
#pragma unroll
        for (int ct = 0; ct < 4; ++ct) {
          int c = ct * 16 + l15;
          float v = acc[rt][ct][rg] + bf2f(T[(size_t)row * 64 + c]) + bv[ct];
          U[(size_t)row * 64 + c] = f2bf(fmaxf(v, 0.0f));
        }
      }
    }
}

// attention over the 2-way stack; 4 threads per node
__global__ __launch_bounds__(256) void attn_kernel(
    const unsigned short* __restrict__ U0, const unsigned short* __restrict__ U1,
    const float* __restrict__ l1w, const float* __restrict__ l1b, const float* __restrict__ l2w,
    float* __restrict__ out, int N) {
  int t = threadIdx.x;
  int node = blockIdx.x * 64 + (t >> 2);
  int q = t & 3;
  if (node >= N) return;
  size_t b0 = (size_t)node * 64;

  float a0[8], a1[8];
#pragma unroll
  for (int i = 0; i < 8; ++i) { a0[i] = l1b[q * 8 + i]; a1[i] = a0[i]; }

  for (int k = 0; k < 64; ++k) {
    float u0 = bf2f(U0[b0 + k]);
    float u1 = bf2f(U1[b0 + k]);
#pragma unroll
    for (int i = 0; i < 8; ++i) {
      float w = l1w[k * 32 + q * 8 + i];
      a0[i] += u0 * w;
      a1[i] += u1 * w;
    }
  }
  float w0 = 0.f, w1 = 0.f;
#pragma unroll
  for (int i = 0; i < 8; ++i) {
    float l2 = l2w[q * 8 + i];
    w0 += tanhf(a0[i]) * l2;
    w1 += tanhf(a1[i]) * l2;
  }
  w0 += __shfl_xor(w0, 1, 4); w0 += __shfl_xor(w0, 2, 4);
  w1 += __shfl_xor(w1, 1, 4); w1 += __shfl_xor(w1, 2, 4);

  float m = fmaxf(w0, w1);
  float e0 = expf(w0 - m), e1 = expf(w1 - m);
  float inv = 1.0f / (e0 + e1);
  float be0 = e0 * inv, be1 = e1 * inv;

#pragma unroll
  for (int j = 0; j < 16; ++j) {
    int c = q * 16 + j;
    out[b0 + c] = be0 * bf2f(U0[b0 + c]) + be1 * bf2f(U1[b0 + c]);
  }
}

static inline size_t au(size_t x) { return (x + 255) & ~(size_t)255; }

extern "C" void kernel_launch(void* const* d_in, const int* in_sizes, int n_in,
                              void* d_out, int out_size, void* d_ws, size_t ws_size,
                              hipStream_t stream) {
  const float* h      = (const float*)d_in[0];
  const float* e_od   = (const float*)d_in[1];
  const float* e_ad   = (const float*)d_in[2];
  const int* src_od   = (const int*)d_in[3];
  const int* dst_od   = (const int*)d_in[4];
  const int* src_ad   = (const int*)d_in[5];
  const int* dst_ad   = (const int*)d_in[6];
  const float* W_src  = (const float*)d_in[7];
  const float* W_dst  = (const float*)d_in[8];
  const float* W_edge = (const float*)d_in[9];
  const float* b_msg  = (const float*)d_in[10];
  const float* W_self = (const float*)d_in[11];
  const float* W_agg  = (const float*)d_in[12];
  const float* b_node = (const float*)d_in[13];
  const float* l1w    = (const float*)d_in[14];
  const float* l1b    = (const float*)d_in[15];
  const float* l2w    = (const float*)d_in[16];
  float* out = (float*)d_out;

  int N = in_sizes[0] / 64;
  int E = in_sizes[1] / 64;
  int NBK = (N + 63) >> 6;  // 64-node dst buckets

  char* ws = (char*)d_ws;
  size_t off = 0;
  int* counts = (int*)(ws + off);   off += au((size_t)2 * NBK * sizeof(int));
  float* agg0 = (float*)(ws + off); off += (size_t)N * 64 * sizeof(float);
  float* agg1 = (float*)(ws + off); off += (size_t)N * 64 * sizeof(float);
  size_t zero_bytes = off;          // counts + agg0 + agg1 contiguous
  int* cursor = (int*)(ws + off);   off += au((size_t)2 * NBK * sizeof(int));
  int* gcur   = (int*)(ws + off);   off += au((size_t)2 * NBK * sizeof(int));
  int2* recs0 = (int2*)(ws + off);  off += au((size_t)E * sizeof(int2));
  int2* recs1 = (int2*)(ws + off);  off += au((size_t)E * sizeof(int2));
  unsigned short* Wf = (unsigned short*)(ws + off); off += au((size_t)10 * 4096 * sizeof(unsigned short));
  size_t NP = au((size_t)N * 64 * sizeof(unsigned short));
  unsigned short* Psrc0 = (unsigned short*)(ws + off); off += NP;
  unsigned short* Pdst0 = (unsigned short*)(ws + off); off += NP;
  unsigned short* Psrc1 = (unsigned short*)(ws + off); off += NP;
  unsigned short* Pdst1 = (unsigned short*)(ws + off); off += NP;
  unsigned short* T0    = (unsigned short*)(ws + off); off += NP;
  unsigned short* T1    = (unsigned short*)(ws + off); off += NP;
  unsigned short* U0 = Psrc0;  // dead after edge pass of graph 0
  unsigned short* U1 = Psrc1;  // dead after edge pass of graph 1

  hipMemsetAsync(ws, 0, zero_bytes, stream);

  // one-time weight prep: fragment-layout bf16 (10 matrices, 1 wave each)
  PrepArgs pw;
  pw.W[0] = W_src;         pw.W[1] = W_dst;
  pw.W[2] = W_src + 4096;  pw.W[3] = W_dst + 4096;
  pw.W[4] = W_self;        pw.W[5] = W_self + 4096;
  pw.W[6] = W_edge;        pw.W[7] = W_edge + 4096;
  pw.W[8] = W_agg;         pw.W[9] = W_agg + 4096;
  prep_w_kernel<<<10, 64, 0, stream>>>(pw, Wf);

  int nb = (N + 255) / 256;
  ProjArgs pa;
  pa.out[0] = Psrc0;
  pa.out[1] = Pdst0;
  pa.out[2] = Psrc1;
  pa.out[3] = Pdst1;
  pa.out[4] = T0;
  pa.out[5] = T1;
  proj_all_kernel<<<dim3(nb, 3), 256, 0, stream>>>(h, Wf, pa, N);

  int nch = (E + CH - 1) / CH;
  hist_kernel<<<dim3(nch, 2), 256, 0, stream>>>(dst_od, dst_ad, counts, E, NBK);
  scan_kernel<<<2, 1024, 0, stream>>>(counts, cursor, gcur, NBK);
  scatterA_kernel<<<dim3(nch, 2), 256, 0, stream>>>(src_od, dst_od, src_ad, dst_ad, gcur,
                                                    recs0, recs1, E, NBK);
  sortB_kernel<<<dim3(NBK, 2), 256, 0, stream>>>(recs0, recs1, cursor, counts, NBK);

  int tiles = (E + 15) / 16;
  int eb = (tiles + 3) / 4;
  EdgeArgs ea;
  ea.e[0] = e_od;  ea.recs[0] = recs0; ea.We[0] = Wf + 6 * 4096; ea.bmsg[0] = b_msg;
  ea.Ps[0] = Psrc0; ea.Pd[0] = Pdst0; ea.agg[0] = agg0;
  ea.e[1] = e_ad;  ea.recs[1] = recs1; ea.We[1] = Wf + 7 * 4096; ea.bmsg[1] = b_msg + 64;
  ea.Ps[1] = Psrc1; ea.Pd[1] = Pdst1; ea.agg[1] = agg1;
  edge_sorted_kernel<<<dim3(eb, 2), 256, 0, stream>>>(ea, E);

  NodeArgs na;
  na.agg[0] = agg0; na.T[0] = T0; na.bn[0] = b_node;      na.U[0] = U0;
  na.agg[1] = agg1; na.T[1] = T1; na.bn[1] = b_node + 64; na.U[1] = U1;
  node_kernel<<<dim3(nb, 2), 256, 0, stream>>>(Wf, na, N);

  attn_kernel<<<(N + 63) / 64, 256, 0, stream>>>(U0, U1, l1w, l1b, l2w, out, N);
}

// Round 16
// 474.615 us; speedup vs baseline: 1.0561x; 1.0561x over previous
//
#include <hip/hip_runtime.h>
#include <hip/hip_bf16.h>

using short8  = __attribute__((ext_vector_type(8))) short;
using ushort8 = __attribute__((ext_vector_type(8))) unsigned short;
using f32x4   = __attribute__((ext_vector_type(4))) float;
using fvec4   = __attribute__((ext_vector_type(4))) float;

#define CH 8192   // edges per hist/scatter block

__device__ inline unsigned short f2bf(float x) {
  union { __hip_bfloat16 b; unsigned short u; } c;
  c.b = __float2bfloat16(x);
  return c.u;
}
__device__ inline float bf2f(unsigned short s) {
  return __uint_as_float(((unsigned int)s) << 16);
}
__device__ inline unsigned int pk2(float lo, float hi) {
  union { __hip_bfloat162 b; unsigned int u; } c;
  c.b = __float22bfloat162_rn(make_float2(lo, hi));
  return c.u;
}
// 8 f32 -> short8 of bf16 via v_cvt_pk_bf16_f32
__device__ inline short8 cvt8(fvec4 a, fvec4 b) {
  union { short8 s; unsigned int u[4]; } r;
  r.u[0] = pk2(a[0], a[1]);
  r.u[1] = pk2(a[2], a[3]);
  r.u[2] = pk2(b[0], b[1]);
  r.u[3] = pk2(b[2], b[3]);
  return r.s;
}

// async 16B global->LDS copy (per-lane global src, wave-uniform LDS base + lane*16)
__device__ inline void gload_lds16(const void* g, void* l) {
  __builtin_amdgcn_global_load_lds(
      (const __attribute__((address_space(1))) void*)g,
      (__attribute__((address_space(3))) void*)l, 16, 0, 0);
}

// B fragments for [64x64] W (row-major f32): lane holds B[k=ks*32+lh*8+i][col=ct*16+l15]
__device__ inline void load_bfrags_f32(const float* __restrict__ W, short8 bfr[2][4], int lane) {
  int l15 = lane & 15, lh = lane >> 4;
#pragma unroll
  for (int ks = 0; ks < 2; ++ks)
#pragma unroll
    for (int ct = 0; ct < 4; ++ct) {
      short8 v;
#pragma unroll
      for (int i = 0; i < 8; ++i)
        v[i] = (short)f2bf(W[(ks * 32 + lh * 8 + i) * 64 + ct * 16 + l15]);
      bfr[ks][ct] = v;
    }
}

// pre-fragmented bf16 W: frag (ks,ct) for lane at Wf[((ks*4+ct)<<9) + (lane<<3)]
__device__ inline void load_bfrags(const unsigned short* __restrict__ Wf, short8 bfr[2][4], int lane) {
#pragma unroll
  for (int ks = 0; ks < 2; ++ks)
#pragma unroll
    for (int ct = 0; ct < 4; ++ct) {
      union { ushort8 u; short8 s; } c;
      c.u = *reinterpret_cast<const ushort8*>(Wf + (((ks * 4 + ct) << 9) + (lane << 3)));
      bfr[ks][ct] = c.s;
    }
}

struct PrepArgs {
  const float* W[10];
};

struct ProjArgs {
  unsigned short* out[6];
};

// fused: blocks 0-1 = exclusive scan of bucket counts (z = blockIdx.x);
//        blocks 2-11 = one-time W fragment prep (matrix blockIdx.x - 2)
__global__ __launch_bounds__(1024) void scan_prep_kernel(const int* __restrict__ counts,
                                                         int* __restrict__ cursor,
                                                         int* __restrict__ gcur, int NBK,
                                                         PrepArgs pw, unsigned short* __restrict__ Wf) {
  if (blockIdx.x >= 2) {
    // ---- prep_w for matrix z = blockIdx.x - 2 (threads 0..63 only) ----
    if (threadIdx.x < 64) {
      int z = blockIdx.x - 2;
      int lane = threadIdx.x;
      short8 bfr[2][4];
      load_bfrags_f32(pw.W[z], bfr, lane);
      unsigned short* dst = Wf + (size_t)z * 4096;
#pragma unroll
      for (int ks = 0; ks < 2; ++ks)
#pragma unroll
        for (int ct = 0; ct < 4; ++ct) {
          union { short8 s; ushort8 u; } c;
          c.s = bfr[ks][ct];
          *reinterpret_cast<ushort8*>(dst + (((ks * 4 + ct) << 9) + (lane << 3))) = c.u;
        }
    }
    return;
  }
  int z = blockIdx.x;
  const int* c = counts + (size_t)z * NBK;
  __shared__ int lds[1024];
  int t = threadIdx.x;
  int carry = 0;
  for (int base = 0; base < NBK; base += 1024) {
    int i = base + t;
    int v = (i < NBK) ? c[i] : 0;
    lds[t] = v;
    __syncthreads();
    for (int off = 1; off < 1024; off <<= 1) {
      int x = (t >= off) ? lds[t - off] : 0;
      __syncthreads();
      lds[t] += x;
      __syncthreads();
    }
    if (i < NBK) {
      int excl = carry + lds[t] - v;
      cursor[(size_t)z * NBK + i] = excl;
      gcur[(size_t)z * NBK + i] = excl;
    }
    carry += lds[1023];
    __syncthreads();
  }
}

// three projections per block (z = 3*blockIdx.y + {0,1,2}); h fragments loaded ONCE
__global__ __launch_bounds__(256) void proj_all_kernel(const float* __restrict__ h,
                                                       const unsigned short* __restrict__ Wf,
                                                       ProjArgs pa, int N) {
  int zb = blockIdx.y * 3;
  int lane = threadIdx.x & 63;
  int wv = threadIdx.x >> 6;
  int rowbase = blockIdx.x * 256 + wv * 64;
  int l15 = lane & 15, lh = lane >> 4;

  short8 afr[4][2];
#pragma unroll
  for (int rt = 0; rt < 4; ++rt) {
    int row = rowbase + rt * 16 + l15;
    int rc = row < N ? row : 0;
    const fvec4* p = reinterpret_cast<const fvec4*>(h + (size_t)rc * 64);
#pragma unroll
    for (int ks = 0; ks < 2; ++ks)
      afr[rt][ks] = cvt8(p[ks * 8 + lh * 2], p[ks * 8 + lh * 2 + 1]);
  }

  for (int zi = 0; zi < 3; ++zi) {
    int z = zb + zi;
    short8 bfr[2][4];
    load_bfrags(Wf + (size_t)z * 4096, bfr, lane);
    unsigned short* __restrict__ out = pa.out[z];

    f32x4 acc[4][4];
#pragma unroll
    for (int rt = 0; rt < 4; ++rt)
#pragma unroll
      for (int ct = 0; ct < 4; ++ct) acc[rt][ct] = (f32x4){0.f, 0.f, 0.f, 0.f};

#pragma unroll
    for (int rt = 0; rt < 4; ++rt)
#pragma unroll
      for (int ks = 0; ks < 2; ++ks)
#pragma unroll
        for (int ct = 0; ct < 4; ++ct)
          acc[rt][ct] = __builtin_amdgcn_mfma_f32_16x16x32_bf16(afr[rt][ks], bfr[ks][ct], acc[rt][ct], 0, 0, 0);

#pragma unroll
    for (int rt = 0; rt < 4; ++rt)
#pragma unroll
      for (int rg = 0; rg < 4; ++rg) {
        int row = rowbase + rt * 16 + lh * 4 + rg;
        if (row < N) {
#pragma unroll
          for (int ct = 0; ct < 4; ++ct)
            out[(size_t)row * 64 + ct * 16 + l15] = f2bf(acc[rt][ct][rg]);
        }
      }
  }
}

// ---- bucket histogram (bin = dst>>6), LDS-aggregated ----
__global__ __launch_bounds__(256) void hist_kernel(const int* __restrict__ dst0, const int* __restrict__ dst1,
                                                   int* __restrict__ counts, int E, int NBK) {
  __shared__ int hcnt[2048];
  int z = blockIdx.y;
  const int* __restrict__ dst = z ? dst1 : dst0;
  int t = threadIdx.x;
  for (int i = t; i < NBK; i += 256) hcnt[i] = 0;
  __syncthreads();
  int base = blockIdx.x * CH;
#pragma unroll 4
  for (int k = 0; k < CH / 256; ++k) {
    int i = base + k * 256 + t;
    if (i < E) atomicAdd(&hcnt[dst[i] >> 6], 1);
  }
  __syncthreads();
  for (int i = t; i < NBK; i += 256) {
    int c = hcnt[i];
    if (c) atomicAdd(&counts[(size_t)z * NBK + i], c);
  }
}

// ---- phase A: bucket scatter with per-block rank aggregation ----
// packed record: x = el | (bin<<21)   (el<2^21, bin<2^11)
//                y = src | (dl<<26)   (src<2^26, dl<64)
__global__ __launch_bounds__(256) void scatterA_kernel(
    const int* __restrict__ src0, const int* __restrict__ dst0,
    const int* __restrict__ src1, const int* __restrict__ dst1,
    int* __restrict__ gcur, int2* __restrict__ recs0, int2* __restrict__ recs1,
    int E, int NBK) {
  __shared__ int lcnt[2048];
  int z = blockIdx.y;
  const int* __restrict__ src = z ? src1 : src0;
  const int* __restrict__ dst = z ? dst1 : dst0;
  int2* __restrict__ recs = z ? recs1 : recs0;
  int t = threadIdx.x;
  for (int i = t; i < NBK; i += 256) lcnt[i] = 0;
  __syncthreads();
  int base = blockIdx.x * CH;
#pragma unroll 4
  for (int k = 0; k < CH / 256; ++k) {
    int i = base + k * 256 + t;
    if (i < E) atomicAdd(&lcnt[dst[i] >> 6], 1);
  }
  __syncthreads();
  for (int i = t; i < NBK; i += 256) {
    int c = lcnt[i];
    lcnt[i] = c ? atomicAdd(&gcur[(size_t)z * NBK + i], c) : 0;
  }
  __syncthreads();
#pragma unroll 4
  for (int k = 0; k < CH / 256; ++k) {
    int i = base + k * 256 + t;
    if (i < E) {
      int d = dst[i], s = src[i];
      int bin = d >> 6, dl = d & 63;
      int pos = atomicAdd(&lcnt[bin], 1);
      recs[pos] = make_int2(i | (bin << 21), s | (dl << 26));
    }
  }
}

// ---- phase B: in-bucket counting sort by dl, IN PLACE (bucket region is block-exclusive) ----
__global__ __launch_bounds__(256) void sortB_kernel(int2* __restrict__ recs0, int2* __restrict__ recs1,
                                                    const int* __restrict__ cursor,
                                                    const int* __restrict__ counts, int NBK) {
  __shared__ int cnt_lds[64];
  __shared__ int cur_lds[64];
  int z = blockIdx.y;
  int b = blockIdx.x;
  int2* __restrict__ recs = z ? recs1 : recs0;
  int start = cursor[(size_t)z * NBK + b];
  int cnt = counts[(size_t)z * NBK + b];
  int t = threadIdx.x;

  for (int cbase = 0; cbase < cnt; cbase += 2048) {
    int ccnt = min(2048, cnt - cbase);
    int2 r[8];
    int dl[8];
    if (t < 64) cnt_lds[t] = 0;
    __syncthreads();
#pragma unroll
    for (int k = 0; k < 8; ++k) {
      int idx = k * 256 + t;
      if (idx < ccnt) {
        r[k] = recs[start + cbase + idx];
        dl[k] = ((unsigned)r[k].y) >> 26;
        atomicAdd(&cnt_lds[dl[k]], 1);
      }
    }
    __syncthreads();
    if (t < 64) {  // wave 0: exclusive prefix over 64 bins
      int c = cnt_lds[t];
      int x = c;
#pragma unroll
      for (int off = 1; off < 64; off <<= 1) {
        int y = __shfl_up(x, off);
        if (t >= off) x += y;
      }
      cur_lds[t] = x - c;
    }
    __syncthreads();
#pragma unroll
    for (int k = 0; k < 8; ++k) {
      int idx = k * 256 + t;
      if (idx < ccnt) {
        int pos = atomicAdd(&cur_lds[dl[k]], 1);
        recs[start + cbase + pos] = r[k];
      }
    }
    __syncthreads();
  }
}

struct EdgeArgs {
  const float* e[2];
  const int2* recs[2];
  const unsigned short* We[2];
  const float* bmsg[2];
  const unsigned short* Ps[2];
  const unsigned short* Pd[2];
  float* agg[2];
};

// ---- edge GEMM over dst-sorted 32-edge tiles (r13 structure: best measured, at the
// random-gather HBM roofline ~2.6 TB/s). acc[2][4]=32 AGPRs; aP/aD=32 VGPRs; ~104 unified.
// order: [Ps/Pd gathers (oldest)] [stage 32 rows (youngest)] [identity MFMAs under vmcnt(8)]
//        [vmcnt0; e-MFMAs from LDS] [relu; register segmented flush]
__global__ __launch_bounds__(256) void edge_sorted_kernel(EdgeArgs ea, int E) {
  __shared__ float e_lds[4][32 * 64];  // 4 waves x 8KB tile buffer (swizzled)

  int z = blockIdx.y;
  const float* __restrict__ e = ea.e[z];
  const int2* __restrict__ recs = ea.recs[z];
  const unsigned short* __restrict__ Psrc = ea.Ps[z];
  const unsigned short* __restrict__ Pdst = ea.Pd[z];
  float* __restrict__ agg = ea.agg[z];

  int lane = threadIdx.x & 63;
  int wv = threadIdx.x >> 6;
  int base = (blockIdx.x * 4 + wv) * 32;
  if (base >= E) return;  // no barriers; LDS is wave-private -> early exit safe
  int l15 = lane & 15, lh = lane >> 4;
  char* lbase = (char*)&e_lds[wv][0];

  // this wave's 32 sorted slots (both half-waves load the same 256B)
  int slot = base + (lane & 31);
  int el = 0, sl = 0, dl = 0;
  if (slot < E) {
    int2 rc = recs[slot];
    el = rc.x & 0x1FFFFF;
    sl = rc.y & 0x3FFFFFF;
    dl = (((rc.x >> 21) & 0x7FF) << 6) | (int)(((unsigned)rc.y) >> 26);
  }

  // ---- group 1: bias, W-fragments, and ALL Ps/Pd gathers (oldest VMEM) ----
  const float* bmsg = ea.bmsg[z];
  float bv[4];
#pragma unroll
  for (int ct = 0; ct < 4; ++ct) bv[ct] = bmsg[ct * 16 + l15];

  short8 bfr[2][4];
  load_bfrags(ea.We[z], bfr, lane);

  ushort8 aP[4], aD[4];  // [rt*2+half], rt in {0,1}
#pragma unroll
  for (int rt = 0; rt < 2; ++rt) {
    int sr = rt * 16 + l15;
    int hr = __shfl(sl, sr);
    int dr = __shfl(dl, sr);
    const ushort8* ps = reinterpret_cast<const ushort8*>(Psrc + ((size_t)hr << 6));
    const ushort8* pd = reinterpret_cast<const ushort8*>(Pdst + ((size_t)dr << 6));
    aP[rt * 2] = ps[lh];
    aP[rt * 2 + 1] = ps[4 + lh];
    aD[rt * 2] = pd[lh];
    aD[rt * 2 + 1] = pd[4 + lh];
  }
  __builtin_amdgcn_sched_barrier(0);

  // ---- group 2: stage the 32 e-rows into swizzled 8KB (youngest VMEM) ----
  // LDS byte for (row r, chunk c[16B]): r*256 + ((c*16) ^ ((r&7)<<4)).
  // Instruction i writes LDS i*1024 + lane*16 -> lane handles r=i*4+(lane>>4),
  // slot s=lane&15, source chunk c = s ^ (r&7).
  int rgrp = lane >> 4;
#pragma unroll
  for (int i = 0; i < 8; ++i) {
    int r = i * 4 + rgrp;
    int er = __shfl(el, r);
    int c = (lane & 15) ^ (r & 7);
    gload_lds16(e + ((size_t)er << 6) + c * 4, lbase + i * 1024);
  }
  __builtin_amdgcn_sched_barrier(0);

  // identity B-fragments: I[k=lh*8+i][col=half*16+l15]
  short8 idf[2];
#pragma unroll
  for (int half = 0; half < 2; ++half) {
    short8 v;
#pragma unroll
    for (int i = 0; i < 8; ++i)
      v[i] = (short)((lh * 8 + i == half * 16 + l15) ? 0x3F80 : 0);
    idf[half] = v;
  }

  // bias folded into accumulator init (per-col broadcast)
  f32x4 acc[2][4];
#pragma unroll
  for (int ct = 0; ct < 4; ++ct) {
    f32x4 bb = (f32x4){bv[ct], bv[ct], bv[ct], bv[ct]};
#pragma unroll
    for (int rt = 0; rt < 2; ++rt) acc[rt][ct] = bb;
  }

  // ---- identity MFMAs: wait only on the 8 gathers (vmcnt(8)); staged rows stay in flight ----
#pragma unroll
  for (int rt = 0; rt < 2; ++rt) {
    union { ushort8 u; short8 s; } aP0, aP1, aD0, aD1;
    aP0.u = aP[rt * 2];
    aP1.u = aP[rt * 2 + 1];
    aD0.u = aD[rt * 2];
    aD1.u = aD[rt * 2 + 1];
    acc[rt][0] = __builtin_amdgcn_mfma_f32_16x16x32_bf16(aP0.s, idf[0], acc[rt][0], 0, 0, 0);
    acc[rt][1] = __builtin_amdgcn_mfma_f32_16x16x32_bf16(aP0.s, idf[1], acc[rt][1], 0, 0, 0);
    acc[rt][2] = __builtin_amdgcn_mfma_f32_16x16x32_bf16(aP1.s, idf[0], acc[rt][2], 0, 0, 0);
    acc[rt][3] = __builtin_amdgcn_mfma_f32_16x16x32_bf16(aP1.s, idf[1], acc[rt][3], 0, 0, 0);
    acc[rt][0] = __builtin_amdgcn_mfma_f32_16x16x32_bf16(aD0.s, idf[0], acc[rt][0], 0, 0, 0);
    acc[rt][1] = __builtin_amdgcn_mfma_f32_16x16x32_bf16(aD0.s, idf[1], acc[rt][1], 0, 0, 0);
    acc[rt][2] = __builtin_amdgcn_mfma_f32_16x16x32_bf16(aD1.s, idf[0], acc[rt][2], 0, 0, 0);
    acc[rt][3] = __builtin_amdgcn_mfma_f32_16x16x32_bf16(aD1.s, idf[1], acc[rt][3], 0, 0, 0);
  }

  // ---- wait staged rows; e-MFMAs from LDS ----
  asm volatile("s_waitcnt vmcnt(0)" ::: "memory");
  __builtin_amdgcn_sched_barrier(0);

#pragma unroll
  for (int rt = 0; rt < 2; ++rt) {
    int rb = rt * 16 + l15;  // buffer row 0..31
    int rowbyte = rb << 8;
    int x = (rb & 7) << 4;
    fvec4 p0 = *reinterpret_cast<const fvec4*>(lbase + rowbyte + (((lh * 2) << 4) ^ x));
    fvec4 p1 = *reinterpret_cast<const fvec4*>(lbase + rowbyte + (((lh * 2 + 1) << 4) ^ x));
    fvec4 p2 = *reinterpret_cast<const fvec4*>(lbase + rowbyte + (((8 + lh * 2) << 4) ^ x));
    fvec4 p3 = *reinterpret_cast<const fvec4*>(lbase + rowbyte + (((9 + lh * 2) << 4) ^ x));
    short8 aE0 = cvt8(p0, p1);
    short8 aE1 = cvt8(p2, p3);
#pragma unroll
    for (int ct = 0; ct < 4; ++ct) {
      acc[rt][ct] = __builtin_amdgcn_mfma_f32_16x16x32_bf16(aE0, bfr[0][ct], acc[rt][ct], 0, 0, 0);
      acc[rt][ct] = __builtin_amdgcn_mfma_f32_16x16x32_bf16(aE1, bfr[1][ct], acc[rt][ct], 0, 0, 0);
    }
  }

  // relu in place
#pragma unroll
  for (int rt = 0; rt < 2; ++rt)
#pragma unroll
    for (int ct = 0; ct < 4; ++ct)
#pragma unroll
      for (int rg = 0; rg < 4; ++rg)
        acc[rt][ct][rg] = fmaxf(acc[rt][ct][rg], 0.f);

  // ---- segmented flush, all in registers (32 rows) ----
  int dprev = __shfl_up(dl, 1);
  unsigned long long bnd = __ballot(lane > 0 && dl != dprev);
  int vrows = min(32, E - base);  // wave-uniform; rows >= vrows are padding

  int r0 = 0;
  while (r0 < vrows) {
    unsigned long long rest = (bnd >> (r0 + 1));
    int r1 = rest ? (r0 + 1 + __builtin_ctzll(rest)) : 32;
    if (r1 > vrows) r1 = vrows;
    int dcur = __shfl(dl, r0);

    float s0 = 0.f, s1 = 0.f, s2 = 0.f, s3 = 0.f;
#pragma unroll
    for (int rt = 0; rt < 2; ++rt) {
      int rs = rt * 16;
      if (r0 <= rs && r1 >= rs + 16) {  // block fully inside (wave-uniform)
#pragma unroll
        for (int rg = 0; rg < 4; ++rg) {
          s0 += acc[rt][0][rg];
          s1 += acc[rt][1][rg];
          s2 += acc[rt][2][rg];
          s3 += acc[rt][3][rg];
        }
      } else if (r0 < rs + 16 && r1 > rs) {  // partial (wave-uniform test, per-lane mask)
#pragma unroll
        for (int rg = 0; rg < 4; ++rg) {
          int row = rs + lh * 4 + rg;
          bool in = (row >= r0) && (row < r1);
          s0 += in ? acc[rt][0][rg] : 0.f;
          s1 += in ? acc[rt][1][rg] : 0.f;
          s2 += in ? acc[rt][2][rg] : 0.f;
          s3 += in ? acc[rt][3][rg] : 0.f;
        }
      }
    }
    // reduce across the 4 lh-lanes of each column group
    s0 += __shfl_xor(s0, 16); s0 += __shfl_xor(s0, 32);
    s1 += __shfl_xor(s1, 16); s1 += __shfl_xor(s1, 32);
    s2 += __shfl_xor(s2, 16); s2 += __shfl_xor(s2, 32);
    s3 += __shfl_xor(s3, 16); s3 += __shfl_xor(s3, 32);
    // lane (lh,l15) owns column lh*16+l15 == lane
    float mine = (lh == 0) ? s0 : (lh == 1) ? s1 : (lh == 2) ? s2 : s3;
    atomicAdd(&agg[(size_t)dcur * 64 + lane], mine);
    r0 = r1;
  }
}

struct NodeArgs {
  const float* agg[2];
  const unsigned short* T[2];
  const float* bn[2];
  unsigned short* U[2];
};

// U = bf16(relu(T + agg@Wagg + b_node)); agg split hi+lo bf16 for accuracy
__global__ __launch_bounds__(256) void node_kernel(const unsigned short* __restrict__ Wf,
                                                   NodeArgs na, int N) {
  int z = blockIdx.y;
  const float* __restrict__ agg = na.agg[z];
  const unsigned short* __restrict__ T = na.T[z];
  const float* __restrict__ bn = na.bn[z];
  unsigned short* __restrict__ U = na.U[z];
  int lane = threadIdx.x & 63;
  int wv = threadIdx.x >> 6;
  int rowbase = blockIdx.x * 256 + wv * 64;
  int l15 = lane & 15, lh = lane >> 4;

  short8 bfr[2][4];
  load_bfrags(Wf + (size_t)(8 + z) * 4096, bfr, lane);

  f32x4 acc[4][4];
#pragma unroll
  for (int rt = 0; rt < 4; ++rt)
#pragma unroll
    for (int ct = 0; ct < 4; ++ct) acc[rt][ct] = (f32x4){0.f, 0.f, 0.f, 0.f};

#pragma unroll
  for (int rt = 0; rt < 4; ++rt) {
    int row = rowbase + rt * 16 + l15;
    int rc = row < N ? row : 0;
    const fvec4* p = reinterpret_cast<const fvec4*>(agg + (size_t)rc * 64);
#pragma unroll
    for (int ks = 0; ks < 2; ++ks) {
      fvec4 p0 = p[ks * 8 + lh * 2], p1 = p[ks * 8 + lh * 2 + 1];
      short8 ahi = cvt8(p0, p1);
      fvec4 q0, q1;
#pragma unroll
      for (int i = 0; i < 4; ++i) {
        q0[i] = p0[i] - bf2f((unsigned short)ahi[i]);
        q1[i] = p1[i] - bf2f((unsigned short)ahi[i + 4]);
      }
      short8 alo = cvt8(q0, q1);
#pragma unroll
      for (int ct = 0; ct < 4; ++ct) {
        acc[rt][ct] = __builtin_amdgcn_mfma_f32_16x16x32_bf16(ahi, bfr[ks][ct], acc[rt][ct], 0, 0, 0);
        acc[rt][ct] = __builtin_amdgcn_mfma_f32_16x16x32_bf16(alo, bfr[ks][ct], acc[rt][ct], 0, 0, 0);
      }
    }
  }

  float bv[4];
#pragma unroll
  for (int ct = 0; ct < 4; ++ct) bv[ct] = bn[ct * 16 + l15];

#pragma unroll
  for (int rt = 0; rt < 4; ++rt)
#pragma unroll
    for (int rg = 0; rg < 4; ++rg) {
      int row = rowbase + rt * 16 + lh * 4 + rg;
      if (row < N) {
#pragma unroll
        for (int ct = 0; ct < 4; ++ct) {
          int c = ct * 16 + l15;
          float v = acc[rt][ct][rg] + bf2f(T[(size_t)row * 64 + c]) + bv[ct];
          U[(size_t)row * 64 + c] = f2bf(fmaxf(v, 0.0f));
        }
      }
    }
}

// attention over the 2-way stack; 4 threads per node
__global__ __launch_bounds__(256) void attn_kernel(
    const unsigned short* __restrict__ U0, const unsigned short* __restrict__ U1,
    const float* __restrict__ l1w, const float* __restrict__ l1b, const float* __restrict__ l2w,
    float* __restrict__ out, int N) {
  int t = threadIdx.x;
  int node = blockIdx.x * 64 + (t >> 2);
  int q = t & 3;
  if (node >= N) return;
  size_t b0 = (size_t)node * 64;

  float a0[8], a1[8];
#pragma unroll
  for (int i = 0; i < 8; ++i) { a0[i] = l1b[q * 8 + i]; a1[i] = a0[i]; }

  for (int k = 0; k < 64; ++k) {
    float u0 = bf2f(U0[b0 + k]);
    float u1 = bf2f(U1[b0 + k]);
#pragma unroll
    for (int i = 0; i < 8; ++i) {
      float w = l1w[k * 32 + q * 8 + i];
      a0[i] += u0 * w;
      a1[i] += u1 * w;
    }
  }
  float w0 = 0.f, w1 = 0.f;
#pragma unroll
  for (int i = 0; i < 8; ++i) {
    float l2 = l2w[q * 8 + i];
    w0 += tanhf(a0[i]) * l2;
    w1 += tanhf(a1[i]) * l2;
  }
  w0 += __shfl_xor(w0, 1, 4); w0 += __shfl_xor(w0, 2, 4);
  w1 += __shfl_xor(w1, 1, 4); w1 += __shfl_xor(w1, 2, 4);

  float m = fmaxf(w0, w1);
  float e0 = expf(w0 - m), e1 = expf(w1 - m);
  float inv = 1.0f / (e0 + e1);
  float be0 = e0 * inv, be1 = e1 * inv;

#pragma unroll
  for (int j = 0; j < 16; ++j) {
    int c = q * 16 + j;
    out[b0 + c] = be0 * bf2f(U0[b0 + c]) + be1 * bf2f(U1[b0 + c]);
  }
}

static inline size_t au(size_t x) { return (x + 255) & ~(size_t)255; }

extern "C" void kernel_launch(void* const* d_in, const int* in_sizes, int n_in,
                              void* d_out, int out_size, void* d_ws, size_t ws_size,
                              hipStream_t stream) {
  const float* h      = (const float*)d_in[0];
  const float* e_od   = (const float*)d_in[1];
  const float* e_ad   = (const float*)d_in[2];
  const int* src_od   = (const int*)d_in[3];
  const int* dst_od   = (const int*)d_in[4];
  const int* src_ad   = (const int*)d_in[5];
  const int* dst_ad   = (const int*)d_in[6];
  const float* W_src  = (const float*)d_in[7];
  const float* W_dst  = (const float*)d_in[8];
  const float* W_edge = (const float*)d_in[9];
  const float* b_msg  = (const float*)d_in[10];
  const float* W_self = (const float*)d_in[11];
  const float* W_agg  = (const float*)d_in[12];
  const float* b_node = (const float*)d_in[13];
  const float* l1w    = (const float*)d_in[14];
  const float* l1b    = (const float*)d_in[15];
  const float* l2w    = (const float*)d_in[16];
  float* out = (float*)d_out;

  int N = in_sizes[0] / 64;
  int E = in_sizes[1] / 64;
  int NBK = (N + 63) >> 6;  // 64-node dst buckets

  char* ws = (char*)d_ws;
  size_t off = 0;
  int* counts = (int*)(ws + off);   off += au((size_t)2 * NBK * sizeof(int));
  float* agg0 = (float*)(ws + off); off += (size_t)N * 64 * sizeof(float);
  float* agg1 = (float*)(ws + off); off += (size_t)N * 64 * sizeof(float);
  size_t zero_bytes = off;          // counts + agg0 + agg1 contiguous
  int* cursor = (int*)(ws + off);   off += au((size_t)2 * NBK * sizeof(int));
  int* gcur   = (int*)(ws + off);   off += au((size_t)2 * NBK * sizeof(int));
  int2* recs0 = (int2*)(ws + off);  off += au((size_t)E * sizeof(int2));
  int2* recs1 = (int2*)(ws + off);  off += au((size_t)E * sizeof(int2));
  unsigned short* Wf = (unsigned short*)(ws + off); off += au((size_t)10 * 4096 * sizeof(unsigned short));
  size_t NP = au((size_t)N * 64 * sizeof(unsigned short));
  unsigned short* Psrc0 = (unsigned short*)(ws + off); off += NP;
  unsigned short* Pdst0 = (unsigned short*)(ws + off); off += NP;
  unsigned short* Psrc1 = (unsigned short*)(ws + off); off += NP;
  unsigned short* Pdst1 = (unsigned short*)(ws + off); off += NP;
  unsigned short* T0    = (unsigned short*)(ws + off); off += NP;
  unsigned short* T1    = (unsigned short*)(ws + off); off += NP;
  unsigned short* U0 = Psrc0;  // dead after edge pass of graph 0
  unsigned short* U1 = Psrc1;  // dead after edge pass of graph 1

  hipMemsetAsync(ws, 0, zero_bytes, stream);

  int nch = (E + CH - 1) / CH;
  hist_kernel<<<dim3(nch, 2), 256, 0, stream>>>(dst_od, dst_ad, counts, E, NBK);

  // fused scan (blocks 0-1) + one-time W fragment prep (blocks 2-11)
  PrepArgs pw;
  pw.W[0] = W_src;         pw.W[1] = W_dst;
  pw.W[2] = W_src + 4096;  pw.W[3] = W_dst + 4096;
  pw.W[4] = W_self;        pw.W[5] = W_self + 4096;
  pw.W[6] = W_edge;        pw.W[7] = W_edge + 4096;
  pw.W[8] = W_agg;         pw.W[9] = W_agg + 4096;
  scan_prep_kernel<<<12, 1024, 0, stream>>>(counts, cursor, gcur, NBK, pw, Wf);

  scatterA_kernel<<<dim3(nch, 2), 256, 0, stream>>>(src_od, dst_od, src_ad, dst_ad, gcur,
                                                    recs0, recs1, E, NBK);
  sortB_kernel<<<dim3(NBK, 2), 256, 0, stream>>>(recs0, recs1, cursor, counts, NBK);

  int nb = (N + 255) / 256;
  ProjArgs pa;
  pa.out[0] = Psrc0;
  pa.out[1] = Pdst0;
  pa.out[2] = Psrc1;
  pa.out[3] = Pdst1;
  pa.out[4] = T0;
  pa.out[5] = T1;
  proj_all_kernel<<<dim3(nb, 2), 256, 0, stream>>>(h, Wf, pa, N);

  int tiles = (E + 31) / 32;
  int eb = (tiles + 3) / 4;
  EdgeArgs ea;
  ea.e[0] = e_od;  ea.recs[0] = recs0; ea.We[0] = Wf + 6 * 4096; ea.bmsg[0] = b_msg;
  ea.Ps[0] = Psrc0; ea.Pd[0] = Pdst0; ea.agg[0] = agg0;
  ea.e[1] = e_ad;  ea.recs[1] = recs1; ea.We[1] = Wf + 7 * 4096; ea.bmsg[1] = b_msg + 64;
  ea.Ps[1] = Psrc1; ea.Pd[1] = Pdst1; ea.agg[1] = agg1;
  edge_sorted_kernel<<<dim3(eb, 2), 256, 0, stream>>>(ea, E);

  NodeArgs na;
  na.agg[0] = agg0; na.T[0] = T0; na.bn[0] = b_node;      na.U[0] = U0;
  na.agg[1] = agg1; na.T[1] = T1; na.bn[1] = b_node + 64; na.U[1] = U1;
  node_kernel<<<dim3(nb, 2), 256, 0, stream>>>(Wf, na, N);

  attn_kernel<<<(N + 63) / 64, 256, 0, stream>>>(U0, U1, l1w, l1b, l2w, out, N);
}